// Round 6
// baseline (172.883 us; speedup 1.0000x reference)
//
#include <hip/hip_runtime.h>
#include <hip/hip_bf16.h>
#include <math.h>

#define BB   16
#define NN   96
#define DD   128
#define NCLS 10

typedef __attribute__((ext_vector_type(8))) short bf16x8;
typedef __attribute__((ext_vector_type(4))) float f32x4;

__device__ __forceinline__ float scalar_as_float(int v) {
    if (v >= -1000000 && v <= 1000000) return (float)v;
    return __int_as_float(v);
}
__device__ __forceinline__ unsigned short f2bf(float f) {
    unsigned u = __float_as_uint(f);
    return (unsigned short)((u + 0x7FFFu + ((u >> 16) & 1u)) >> 16);
}
__device__ __forceinline__ float bf2f(unsigned short h) {
    return __uint_as_float(((unsigned)h) << 16);
}

// ---------------- one-time: pack W2 into MFMA B-fragments, bf16 hi + lo ----------------
// frag-major: [dtile 0..7][kchunk 0..3][lane 0..63][e 0..7]
// B-frag (16x16x32): lane l holds B[k = kc*32 + (l>>4)*8 + e][col = dt*16 + (l&15)]
__global__ __launch_bounds__(256) void k_w2prep(
    const float* __restrict__ W2, unsigned short* __restrict__ whi,
    unsigned short* __restrict__ wlo)
{
    const int dt = blockIdx.x;
    const int kc = threadIdx.x >> 6;
    const int l  = threadIdx.x & 63;
    const int base = ((dt * 4 + kc) * 64 + l) * 8;
    const int c = dt * 16 + (l & 15);
#pragma unroll
    for (int e = 0; e < 8; ++e) {
        const int k = kc * 32 + (l >> 4) * 8 + e;
        const float wv = W2[k * DD + c];
        const unsigned short h = f2bf(wv);
        whi[base + e] = h;
        wlo[base + e] = f2bf(wv - bf2f(h));
    }
}

// ---------------- one-time: AT[b][i][j] = A[b][j][i] ----------------
__global__ __launch_bounds__(256) void k_atrans(
    const float* __restrict__ A, float* __restrict__ AT)
{
    const int b = blockIdx.x;
    __shared__ float tile[NN][NN + 1];
    for (int idx = threadIdx.x; idx < NN * NN; idx += 256)
        tile[idx / NN][idx % NN] = A[b * NN * NN + idx];
    __syncthreads();
    for (int idx = threadIdx.x; idx < NN * NN; idx += 256) {
        const int i = idx / NN, j = idx % NN;
        AT[b * NN * NN + idx] = tile[j][i];
    }
}

// ---------------- init: x = e = embed_W[tok]; e_proj = e@W1e; xjA = e@W1x ----------------
__global__ __launch_bounds__(128) void k_init(
    const int* __restrict__ tok, const float* __restrict__ embed_W,
    const float* __restrict__ W1, float* __restrict__ x,
    float* __restrict__ e_proj, float* __restrict__ xj)
{
    const int row = blockIdx.y * NN + blockIdx.x;
    const int t = threadIdx.x;
    __shared__ float e_s[DD];
    const float ev = embed_W[tok[row] * DD + t];
    e_s[t] = ev;
    x[row * DD + t] = ev;
    __syncthreads();
    float a1 = 0.f, a2 = 0.f;
#pragma unroll 8
    for (int k = 0; k < DD; ++k) {
        const float e = e_s[k];
        a1 = fmaf(e, W1[k * DD + t], a1);
        a2 = fmaf(e, W1[(DD + k) * DD + t], a2);
    }
    e_proj[row * DD + t] = a1;
    xj[row * DD + t]     = a2;
}

#define MFMA(A, B, C) __builtin_amdgcn_mfma_f32_16x16x32_bf16(A, B, C, 0, 0, 0)

// ---------------- fully-fused per-round kernel: block=(b,i), 4 waves ----------------
// Wave w owns d-tiles {w, w+4}; all 16 B-frags (hi/lo x 2dt x 4kc) in NAMED registers.
// 256 thr -> per-block LDS read traffic halves vs 8-wave (4 x 24KB H sweeps).
// launch_bounds(256,4): 128-VGPR budget, 4 blocks/CU target.
template<int FIN>
__global__ __launch_bounds__(256, 4) void k_round(
    const float* __restrict__ AT, const float* __restrict__ e_proj,
    const float* __restrict__ xj_in, const float* __restrict__ b1,
    const unsigned short* __restrict__ w2hi, const unsigned short* __restrict__ w2lo,
    const float* __restrict__ b2,
    const float* __restrict__ Wo1, const float* __restrict__ bo1,
    const float* __restrict__ Wo2, const float* __restrict__ embed_W,
    const float* __restrict__ W1x, const int* __restrict__ tau_p,
    float* __restrict__ x, float* __restrict__ xj_out,
    float* __restrict__ out, float* __restrict__ x_all)
{
    const int i = blockIdx.x;
    const int b = blockIdx.y;
    const int t = threadIdx.x;   // 0..255
    const int w = t >> 6;        // wave 0..3: d-tiles w, w+4
    const int l = t & 63;
    const int row = b * NN + i;

    __shared__ __align__(16) unsigned short hs[NN * DD];  // XOR-swizzled bf16 H (24 KB)
    __shared__ float v_s[DD];
    __shared__ float ac_s[NN];
    __shared__ float agg_s[DD];
    __shared__ float xn_s[DD];
    __shared__ float part_s[2][DD];
    __shared__ float wred[2][NCLS];

    if (t < DD) v_s[t] = e_proj[row * DD + t] + b1[t];
    else if (t < DD + NN) ac_s[t - DD] = AT[row * NN + (t - DD)];

    // B-fragments: named registers, loaded ONCE (watch VGPR_Count for reload regression)
    const bf16x8* WH = (const bf16x8*)w2hi;
    const bf16x8* WL = (const bf16x8*)w2lo;
    const int f0 = (w * 4) * 64 + l;            // dt0 = w
    const int f1 = ((w + 4) * 4) * 64 + l;      // dt1 = w+4
    const bf16x8 bh00 = WH[f0],        bl00 = WL[f0];
    const bf16x8 bh01 = WH[f0 + 64],   bl01 = WL[f0 + 64];
    const bf16x8 bh02 = WH[f0 + 128],  bl02 = WL[f0 + 128];
    const bf16x8 bh03 = WH[f0 + 192],  bl03 = WL[f0 + 192];
    const bf16x8 bh10 = WH[f1],        bl10 = WL[f1];
    const bf16x8 bh11 = WH[f1 + 64],   bl11 = WL[f1 + 64];
    const bf16x8 bh12 = WH[f1 + 128],  bl12 = WL[f1 + 128];
    const bf16x8 bh13 = WH[f1 + 192],  bl13 = WL[f1 + 192];
    const float b2v0 = b2[w * 16 + (l & 15)];
    const float b2v1 = b2[64 + w * 16 + (l & 15)];
    __syncthreads();

    {   // H = relu(v + xj) -> bf16 LDS, swizzled: short_idx ^ ((row&7)<<3)
        const float4* src = (const float4*)(xj_in + b * NN * DD);
        const float4* vv  = (const float4*)v_s;
#pragma unroll
        for (int it = 0; it < 12; ++it) {
            const int idx = t + it * 256;          // 0..3071
            const int j = idx >> 5, k4 = (idx & 31) << 2;
            const float4 u = src[idx];
            const float4 v = vv[idx & 31];
            ushort4 hh;
            hh.x = f2bf(fmaxf(u.x + v.x, 0.f));
            hh.y = f2bf(fmaxf(u.y + v.y, 0.f));
            hh.z = f2bf(fmaxf(u.z + v.z, 0.f));
            hh.w = f2bf(fmaxf(u.w + v.w, 0.f));
            *(ushort4*)&hs[(j * DD + k4) ^ ((j & 7) << 3)] = hh;
        }
    }
    __syncthreads();

    // GEMM: wave sweeps six 16-row j-tiles for d-tiles {w, w+4} (hi+lo MFMA)
    float aggp0 = 0.f, aggp1 = 0.f;
#pragma unroll
    for (int jt = 0; jt < 6; ++jt) {
        const int r16 = jt * 16 + (l & 15);
        const int ko  = (l >> 4) * 8;
        const int sw  = (r16 & 7) << 3;
        const bf16x8 a0 = *(const bf16x8*)&hs[(r16 * DD + ko     ) ^ sw];
        const bf16x8 a1 = *(const bf16x8*)&hs[(r16 * DD + ko + 32) ^ sw];
        const bf16x8 a2 = *(const bf16x8*)&hs[(r16 * DD + ko + 64) ^ sw];
        const bf16x8 a3 = *(const bf16x8*)&hs[(r16 * DD + ko + 96) ^ sw];
        f32x4 ch0 = {0.f, 0.f, 0.f, 0.f}, cl0 = {0.f, 0.f, 0.f, 0.f};
        f32x4 ch1 = {0.f, 0.f, 0.f, 0.f}, cl1 = {0.f, 0.f, 0.f, 0.f};
        ch0 = MFMA(a0, bh00, ch0);  cl0 = MFMA(a0, bl00, cl0);
        ch1 = MFMA(a0, bh10, ch1);  cl1 = MFMA(a0, bl10, cl1);
        ch0 = MFMA(a1, bh01, ch0);  cl0 = MFMA(a1, bl01, cl0);
        ch1 = MFMA(a1, bh11, ch1);  cl1 = MFMA(a1, bl11, cl1);
        ch0 = MFMA(a2, bh02, ch0);  cl0 = MFMA(a2, bl02, cl0);
        ch1 = MFMA(a2, bh12, ch1);  cl1 = MFMA(a2, bl12, cl1);
        ch0 = MFMA(a3, bh03, ch0);  cl0 = MFMA(a3, bl03, cl0);
        ch1 = MFMA(a3, bh13, ch1);  cl1 = MFMA(a3, bl13, cl1);
        const f32x4 m0 = ch0 + cl0;
        const f32x4 m1 = ch1 + cl1;
        // C-frag: col = l&15, row j = jt*16 + (l>>4)*4 + r
#pragma unroll
        for (int r = 0; r < 4; ++r) {
            const float a = ac_s[jt * 16 + (l >> 4) * 4 + r];
            aggp0 = fmaf(a, fmaxf(m0[r] + b2v0, 0.f), aggp0);
            aggp1 = fmaf(a, fmaxf(m1[r] + b2v1, 0.f), aggp1);
        }
    }
    aggp0 += __shfl_xor(aggp0, 16); aggp0 += __shfl_xor(aggp0, 32);
    aggp1 += __shfl_xor(aggp1, 16); aggp1 += __shfl_xor(aggp1, 32);
    if (l < 16) {
        agg_s[w * 16 + l]      = aggp0;
        agg_s[64 + w * 16 + l] = aggp1;
    }
    __syncthreads();

    // ---- epilogue: x-update + head(+discretize+xj) fused, block-local ----
    float xn = 0.f;
    if (t < DD) {
        xn = x[row * DD + t] + agg_s[t];
        xn_s[t] = xn;
    }
    __syncthreads();

    {   // hid partials: half q sums 64 k's for output h
        const int q = t >> 7, h = t & 127;
        float pp = 0.f;
#pragma unroll
        for (int kk = 0; kk < 64; ++kk) {
            const int k = q * 64 + kk;
            pp = fmaf(xn_s[k], Wo1[k * DD + h], pp);
        }
        part_s[q][h] = pp;
    }
    __syncthreads();

    if (t < DD) {   // waves 0,1 fully active: butterfly is safe
        const float hid = fmaxf(part_s[0][t] + part_s[1][t] + bo1[t], 0.f);
        float lgp[NCLS];
#pragma unroll
        for (int c = 0; c < NCLS; ++c) lgp[c] = hid * Wo2[t * NCLS + c];
#pragma unroll
        for (int s = 1; s < 64; s <<= 1) {
#pragma unroll
            for (int c = 0; c < NCLS; ++c) lgp[c] += __shfl_xor(lgp[c], s);
        }
        if (l == 0) {
#pragma unroll
            for (int c = 0; c < NCLS; ++c) wred[w][c] = lgp[c];
        }
    }
    __syncthreads();

    if (FIN) {
        if (t < NCLS) {
            const float lg = wred[0][t] + wred[1][t];
            x_all[row * NCLS + t] = lg;
            if (i == 0) out[b * NCLS + t] = lg;
        }
        return;
    }

    // discretize: redundant per-thread softmax, then x += p @ centroids
    if (t < DD) {
        float lg[NCLS];
        float mx = -1e30f;
#pragma unroll
        for (int c = 0; c < NCLS; ++c) {
            lg[c] = wred[0][c] + wred[1][c];
            mx = fmaxf(mx, lg[c]);
        }
        const float inv_tau = 1.f / scalar_as_float(tau_p[0]);
        float p[NCLS], den = 0.f;
#pragma unroll
        for (int c = 0; c < NCLS; ++c) { p[c] = expf((lg[c] - mx) * inv_tau); den += p[c]; }
        const float invden = 1.f / den;
#pragma unroll
        for (int c = 0; c < NCLS; ++c)
            xn = fmaf(p[c] * invden, embed_W[(4 + c) * DD + t], xn);
        x[row * DD + t] = xn;
        xn_s[t] = xn;
    }
    __syncthreads();

    {   // next round's xj = xn @ W1x
        const int q = t >> 7, h = t & 127;
        float pp = 0.f;
#pragma unroll
        for (int kk = 0; kk < 64; ++kk) {
            const int k = q * 64 + kk;
            pp = fmaf(xn_s[k], W1x[k * DD + h], pp);
        }
        part_s[q][h] = pp;
    }
    __syncthreads();
    if (t < DD)
        xj_out[row * DD + t] = part_s[0][t] + part_s[1][t];
}

extern "C" void kernel_launch(void* const* d_in, const int* in_sizes, int n_in,
                              void* d_out, int out_size, void* d_ws, size_t ws_size,
                              hipStream_t stream)
{
    (void)in_sizes; (void)n_in; (void)out_size; (void)ws_size;
    const int*   tok     = (const int*)d_in[0];
    const float* Aab     = (const float*)d_in[1];
    const float* embed_W = (const float*)d_in[2];
    const float* W1      = (const float*)d_in[3];
    const float* b1      = (const float*)d_in[4];
    const float* W2      = (const float*)d_in[5];
    const float* b2      = (const float*)d_in[6];
    const float* Wo1     = (const float*)d_in[7];
    const float* bo1     = (const float*)d_in[8];
    const float* Wo2     = (const float*)d_in[9];
    const int*   tau_p   = (const int*)d_in[11];

    float* out   = (float*)d_out;
    float* x_all = out + BB * NCLS;

    float* ws     = (float*)d_ws;
    float* x      = ws;                                   // 196608 f
    float* e_proj = ws + BB * NN * DD;                    // 196608 f
    float* xjA    = ws + 2 * BB * NN * DD;                // 196608 f
    float* xjB    = ws + 3 * BB * NN * DD;                // 196608 f
    float* ATr    = ws + 4 * BB * NN * DD;                // 147456 f
    unsigned short* w2hi = (unsigned short*)(ws + 4 * BB * NN * DD + BB * NN * NN);
    unsigned short* w2lo = w2hi + DD * DD;

    const float* W1x = W1 + DD * DD;

    dim3 grid(NN, BB);
    k_w2prep<<<8, 256, 0, stream>>>(W2, w2hi, w2lo);
    k_atrans<<<BB, 256, 0, stream>>>(Aab, ATr);
    k_init<<<grid, 128, 0, stream>>>(tok, embed_W, W1, x, e_proj, xjA);
    for (int r = 0; r < 5; ++r) {
        const float* xin = (r & 1) ? xjB : xjA;
        float*       xot = (r & 1) ? xjA : xjB;
        if (r < 4)
            k_round<0><<<grid, 256, 0, stream>>>(ATr, e_proj, xin, b1, w2hi, w2lo, b2,
                                                 Wo1, bo1, Wo2, embed_W, W1x, tau_p,
                                                 x, xot, out, x_all);
        else
            k_round<1><<<grid, 256, 0, stream>>>(ATr, e_proj, xin, b1, w2hi, w2lo, b2,
                                                 Wo1, bo1, Wo2, embed_W, W1x, tau_p,
                                                 x, xot, out, x_all);
    }
}

// Round 7
// 138.492 us; speedup vs baseline: 1.2483x; 1.2483x over previous
//
#include <hip/hip_runtime.h>
#include <hip/hip_bf16.h>
#include <math.h>

#define BB   16
#define NN   96
#define DD   128
#define NCLS 10

typedef __attribute__((ext_vector_type(8))) short bf16x8;
typedef __attribute__((ext_vector_type(4))) float f32x4;

__device__ __forceinline__ float scalar_as_float(int v) {
    if (v >= -1000000 && v <= 1000000) return (float)v;
    return __int_as_float(v);
}
__device__ __forceinline__ unsigned short f2bf(float f) {
    unsigned u = __float_as_uint(f);
    return (unsigned short)((u + 0x7FFFu + ((u >> 16) & 1u)) >> 16);
}
__device__ __forceinline__ float bf2f(unsigned short h) {
    return __uint_as_float(((unsigned)h) << 16);
}

// ---------------- one-time: pack W2 into MFMA B-fragments, bf16 hi + lo ----------------
// frag-major: [dtile 0..7][kchunk 0..3][lane 0..63][e 0..7]
// B-frag (16x16x32): lane l holds B[k = kc*32 + (l>>4)*8 + e][col = dt*16 + (l&15)]
__global__ __launch_bounds__(256) void k_w2prep(
    const float* __restrict__ W2, unsigned short* __restrict__ whi,
    unsigned short* __restrict__ wlo)
{
    const int dt = blockIdx.x;
    const int kc = threadIdx.x >> 6;
    const int l  = threadIdx.x & 63;
    const int base = ((dt * 4 + kc) * 64 + l) * 8;
    const int c = dt * 16 + (l & 15);
#pragma unroll
    for (int e = 0; e < 8; ++e) {
        const int k = kc * 32 + (l >> 4) * 8 + e;
        const float wv = W2[k * DD + c];
        const unsigned short h = f2bf(wv);
        whi[base + e] = h;
        wlo[base + e] = f2bf(wv - bf2f(h));
    }
}

// ---------------- one-time: AT[b][i][j] = A[b][j][i] ----------------
__global__ __launch_bounds__(256) void k_atrans(
    const float* __restrict__ A, float* __restrict__ AT)
{
    const int b = blockIdx.x;
    __shared__ float tile[NN][NN + 1];
    for (int idx = threadIdx.x; idx < NN * NN; idx += 256)
        tile[idx / NN][idx % NN] = A[b * NN * NN + idx];
    __syncthreads();
    for (int idx = threadIdx.x; idx < NN * NN; idx += 256) {
        const int i = idx / NN, j = idx % NN;
        AT[b * NN * NN + idx] = tile[j][i];
    }
}

// ---------------- init: x = e = embed_W[tok]; e_proj = e@W1e; xjA = e@W1x ----------------
__global__ __launch_bounds__(128) void k_init(
    const int* __restrict__ tok, const float* __restrict__ embed_W,
    const float* __restrict__ W1, float* __restrict__ x,
    float* __restrict__ e_proj, float* __restrict__ xj)
{
    const int row = blockIdx.y * NN + blockIdx.x;
    const int t = threadIdx.x;
    __shared__ float e_s[DD];
    const float ev = embed_W[tok[row] * DD + t];
    e_s[t] = ev;
    x[row * DD + t] = ev;
    __syncthreads();
    float a1 = 0.f, a2 = 0.f;
#pragma unroll 8
    for (int k = 0; k < DD; ++k) {
        const float e = e_s[k];
        a1 = fmaf(e, W1[k * DD + t], a1);
        a2 = fmaf(e, W1[(DD + k) * DD + t], a2);
    }
    e_proj[row * DD + t] = a1;
    xj[row * DD + t]     = a2;
}

#define MFMA(A, B, C) __builtin_amdgcn_mfma_f32_16x16x32_bf16(A, B, C, 0, 0, 0)

// ---------------- fully-fused per-round kernel: block=(b,i), 8 waves ----------------
// Wave w owns d-tile w. B-frags pinned in registers via asm-touch: without it the
// compiler REMATERIALIZES the loads inside the jt-loop (R3/R6 evidence: VGPR=40/60 <
// frag footprint), re-reading 384KB/block from L2 = the dominant cost (~17us/CU).
template<int FIN>
__global__ __launch_bounds__(512, 4) void k_round(
    const float* __restrict__ AT, const float* __restrict__ e_proj,
    const float* __restrict__ xj_in, const float* __restrict__ b1,
    const unsigned short* __restrict__ w2hi, const unsigned short* __restrict__ w2lo,
    const float* __restrict__ b2,
    const float* __restrict__ Wo1, const float* __restrict__ bo1,
    const float* __restrict__ Wo2, const float* __restrict__ embed_W,
    const float* __restrict__ W1x, const int* __restrict__ tau_p,
    float* __restrict__ x, float* __restrict__ xj_out,
    float* __restrict__ out, float* __restrict__ x_all)
{
    const int i = blockIdx.x;
    const int b = blockIdx.y;
    const int t = threadIdx.x;   // 0..511
    const int w = t >> 6;        // wave = d-tile 0..7
    const int l = t & 63;
    const int row = b * NN + i;

    __shared__ __align__(16) unsigned short hs[NN * DD];  // XOR-swizzled bf16 H (24 KB)
    __shared__ float v_s[DD];
    __shared__ float ac_s[NN];
    __shared__ float agg_s[DD];
    __shared__ float xn_s[DD];
    __shared__ float part_s[4][DD];
    __shared__ float wred[2][NCLS];

    if (t < DD) v_s[t] = e_proj[row * DD + t] + b1[t];
    else if (t < DD + NN) ac_s[t - DD] = AT[row * NN + (t - DD)];

    // B-fragments: load once, then PIN with asm-touch (blocks rematerialization)
    const bf16x8* WH = (const bf16x8*)w2hi;
    const bf16x8* WL = (const bf16x8*)w2lo;
    const int f0 = (w * 4) * 64 + l;
    bf16x8 bh0 = WH[f0],       bl0 = WL[f0];
    bf16x8 bh1 = WH[f0 + 64],  bl1 = WL[f0 + 64];
    bf16x8 bh2 = WH[f0 + 128], bl2 = WL[f0 + 128];
    bf16x8 bh3 = WH[f0 + 192], bl3 = WL[f0 + 192];
    asm volatile("" : "+v"(bh0), "+v"(bh1), "+v"(bh2), "+v"(bh3),
                      "+v"(bl0), "+v"(bl1), "+v"(bl2), "+v"(bl3));
    const float b2v = b2[w * 16 + (l & 15)];
    __syncthreads();

    {   // H = relu(v + xj) -> bf16 LDS, swizzled: short_idx ^ ((row&7)<<3)
        const float4* src = (const float4*)(xj_in + b * NN * DD);
        const float4* vv  = (const float4*)v_s;
#pragma unroll
        for (int it = 0; it < 6; ++it) {
            const int idx = t + it * 512;          // 0..3071
            const int j = idx >> 5, k4 = (idx & 31) << 2;
            const float4 u = src[idx];
            const float4 v = vv[idx & 31];
            ushort4 hh;
            hh.x = f2bf(fmaxf(u.x + v.x, 0.f));
            hh.y = f2bf(fmaxf(u.y + v.y, 0.f));
            hh.z = f2bf(fmaxf(u.z + v.z, 0.f));
            hh.w = f2bf(fmaxf(u.w + v.w, 0.f));
            *(ushort4*)&hs[(j * DD + k4) ^ ((j & 7) << 3)] = hh;
        }
    }
    __syncthreads();

    // GEMM: wave sweeps six 16-row j-tiles for its one 16-col d-tile (hi+lo MFMA)
    float aggp = 0.f;
#pragma unroll
    for (int jt = 0; jt < 6; ++jt) {
        const int r16 = jt * 16 + (l & 15);
        const int ko  = (l >> 4) * 8;
        const int sw  = (r16 & 7) << 3;
        const bf16x8 a0 = *(const bf16x8*)&hs[(r16 * DD + ko     ) ^ sw];
        const bf16x8 a1 = *(const bf16x8*)&hs[(r16 * DD + ko + 32) ^ sw];
        const bf16x8 a2 = *(const bf16x8*)&hs[(r16 * DD + ko + 64) ^ sw];
        const bf16x8 a3 = *(const bf16x8*)&hs[(r16 * DD + ko + 96) ^ sw];
        f32x4 ch = {0.f, 0.f, 0.f, 0.f}, cl = {0.f, 0.f, 0.f, 0.f};
        ch = MFMA(a0, bh0, ch);  cl = MFMA(a0, bl0, cl);
        ch = MFMA(a1, bh1, ch);  cl = MFMA(a1, bl1, cl);
        ch = MFMA(a2, bh2, ch);  cl = MFMA(a2, bl2, cl);
        ch = MFMA(a3, bh3, ch);  cl = MFMA(a3, bl3, cl);
        const f32x4 m = ch + cl;
        // C-frag: col = l&15, row j = jt*16 + (l>>4)*4 + r
#pragma unroll
        for (int r = 0; r < 4; ++r) {
            const float a = ac_s[jt * 16 + (l >> 4) * 4 + r];
            aggp = fmaf(a, fmaxf(m[r] + b2v, 0.f), aggp);
        }
    }
    aggp += __shfl_xor(aggp, 16);
    aggp += __shfl_xor(aggp, 32);
    if (l < 16) agg_s[w * 16 + l] = aggp;
    __syncthreads();

    // ---- epilogue: x-update + head(+discretize+xj) fused, block-local ----
    float xn = 0.f;
    if (t < DD) {
        xn = x[row * DD + t] + agg_s[t];
        xn_s[t] = xn;
    }
    __syncthreads();

    {   // hid partials: quarter q sums 32 k's for output h
        const int q = t >> 7, h = t & 127;
        float pp = 0.f;
#pragma unroll
        for (int kk = 0; kk < 32; ++kk) {
            const int k = q * 32 + kk;
            pp = fmaf(xn_s[k], Wo1[k * DD + h], pp);
        }
        part_s[q][h] = pp;
    }
    __syncthreads();

    if (t < DD) {   // waves 0,1 fully active: butterfly is safe
        const float hid = fmaxf(part_s[0][t] + part_s[1][t] + part_s[2][t] + part_s[3][t]
                                + bo1[t], 0.f);
        float lgp[NCLS];
#pragma unroll
        for (int c = 0; c < NCLS; ++c) lgp[c] = hid * Wo2[t * NCLS + c];
#pragma unroll
        for (int s = 1; s < 64; s <<= 1) {
#pragma unroll
            for (int c = 0; c < NCLS; ++c) lgp[c] += __shfl_xor(lgp[c], s);
        }
        if (l == 0) {
#pragma unroll
            for (int c = 0; c < NCLS; ++c) wred[w][c] = lgp[c];
        }
    }
    __syncthreads();

    if (FIN) {
        if (t < NCLS) {
            const float lg = wred[0][t] + wred[1][t];
            x_all[row * NCLS + t] = lg;
            if (i == 0) out[b * NCLS + t] = lg;
        }
        return;
    }

    // discretize: redundant per-thread softmax, then x += p @ centroids
    if (t < DD) {
        float lg[NCLS];
        float mx = -1e30f;
#pragma unroll
        for (int c = 0; c < NCLS; ++c) {
            lg[c] = wred[0][c] + wred[1][c];
            mx = fmaxf(mx, lg[c]);
        }
        const float inv_tau = 1.f / scalar_as_float(tau_p[0]);
        float p[NCLS], den = 0.f;
#pragma unroll
        for (int c = 0; c < NCLS; ++c) { p[c] = expf((lg[c] - mx) * inv_tau); den += p[c]; }
        const float invden = 1.f / den;
#pragma unroll
        for (int c = 0; c < NCLS; ++c)
            xn = fmaf(p[c] * invden, embed_W[(4 + c) * DD + t], xn);
        x[row * DD + t] = xn;
        xn_s[t] = xn;
    }
    __syncthreads();

    {   // next round's xj = xn @ W1x
        const int q = t >> 7, h = t & 127;
        float pp = 0.f;
#pragma unroll
        for (int kk = 0; kk < 32; ++kk) {
            const int k = q * 32 + kk;
            pp = fmaf(xn_s[k], W1x[k * DD + h], pp);
        }
        part_s[q][h] = pp;
    }
    __syncthreads();
    if (t < DD)
        xj_out[row * DD + t] = part_s[0][t] + part_s[1][t] + part_s[2][t] + part_s[3][t];
}

extern "C" void kernel_launch(void* const* d_in, const int* in_sizes, int n_in,
                              void* d_out, int out_size, void* d_ws, size_t ws_size,
                              hipStream_t stream)
{
    (void)in_sizes; (void)n_in; (void)out_size; (void)ws_size;
    const int*   tok     = (const int*)d_in[0];
    const float* Aab     = (const float*)d_in[1];
    const float* embed_W = (const float*)d_in[2];
    const float* W1      = (const float*)d_in[3];
    const float* b1      = (const float*)d_in[4];
    const float* W2      = (const float*)d_in[5];
    const float* b2      = (const float*)d_in[6];
    const float* Wo1     = (const float*)d_in[7];
    const float* bo1     = (const float*)d_in[8];
    const float* Wo2     = (const float*)d_in[9];
    const int*   tau_p   = (const int*)d_in[11];

    float* out   = (float*)d_out;
    float* x_all = out + BB * NCLS;

    float* ws     = (float*)d_ws;
    float* x      = ws;                                   // 196608 f
    float* e_proj = ws + BB * NN * DD;                    // 196608 f
    float* xjA    = ws + 2 * BB * NN * DD;                // 196608 f
    float* xjB    = ws + 3 * BB * NN * DD;                // 196608 f
    float* ATr    = ws + 4 * BB * NN * DD;                // 147456 f
    unsigned short* w2hi = (unsigned short*)(ws + 4 * BB * NN * DD + BB * NN * NN);
    unsigned short* w2lo = w2hi + DD * DD;

    const float* W1x = W1 + DD * DD;

    dim3 grid(NN, BB);
    k_w2prep<<<8, 256, 0, stream>>>(W2, w2hi, w2lo);
    k_atrans<<<BB, 256, 0, stream>>>(Aab, ATr);
    k_init<<<grid, 128, 0, stream>>>(tok, embed_W, W1, x, e_proj, xjA);
    for (int r = 0; r < 5; ++r) {
        const float* xin = (r & 1) ? xjB : xjA;
        float*       xot = (r & 1) ? xjA : xjB;
        if (r < 4)
            k_round<0><<<grid, 512, 0, stream>>>(ATr, e_proj, xin, b1, w2hi, w2lo, b2,
                                                 Wo1, bo1, Wo2, embed_W, W1x, tau_p,
                                                 x, xot, out, x_all);
        else
            k_round<1><<<grid, 512, 0, stream>>>(ATr, e_proj, xin, b1, w2hi, w2lo, b2,
                                                 Wo1, bo1, Wo2, embed_W, W1x, tau_p,
                                                 x, xot, out, x_all);
    }
}

// Round 8
// 127.846 us; speedup vs baseline: 1.3523x; 1.0833x over previous
//
#include <hip/hip_runtime.h>
#include <hip/hip_bf16.h>
#include <math.h>

#define BB   16
#define NN   96
#define DD   128
#define NCLS 10

typedef __attribute__((ext_vector_type(8))) short bf16x8;
typedef __attribute__((ext_vector_type(4))) float f32x4;

__device__ __forceinline__ float scalar_as_float(int v) {
    if (v >= -1000000 && v <= 1000000) return (float)v;
    return __int_as_float(v);
}
__device__ __forceinline__ unsigned short f2bf(float f) {
    unsigned u = __float_as_uint(f);
    return (unsigned short)((u + 0x7FFFu + ((u >> 16) & 1u)) >> 16);
}
__device__ __forceinline__ float bf2f(unsigned short h) {
    return __uint_as_float(((unsigned)h) << 16);
}

// ---------------- one-time: pack W2 into MFMA B-fragments, bf16 hi + lo ----------------
// frag-major: [dtile 0..7][kchunk 0..3][lane 0..63][e 0..7]
// B-frag (16x16x32): lane l holds B[k = kc*32 + (l>>4)*8 + e][col = dt*16 + (l&15)]
__global__ __launch_bounds__(256) void k_w2prep(
    const float* __restrict__ W2, unsigned short* __restrict__ whi,
    unsigned short* __restrict__ wlo)
{
    const int dt = blockIdx.x;
    const int kc = threadIdx.x >> 6;
    const int l  = threadIdx.x & 63;
    const int base = ((dt * 4 + kc) * 64 + l) * 8;
    const int c = dt * 16 + (l & 15);
#pragma unroll
    for (int e = 0; e < 8; ++e) {
        const int k = kc * 32 + (l >> 4) * 8 + e;
        const float wv = W2[k * DD + c];
        const unsigned short h = f2bf(wv);
        whi[base + e] = h;
        wlo[base + e] = f2bf(wv - bf2f(h));
    }
}

// ---------------- one-time: AT[b][i][j] = A[b][j][i] ----------------
__global__ __launch_bounds__(256) void k_atrans(
    const float* __restrict__ A, float* __restrict__ AT)
{
    const int b = blockIdx.x;
    __shared__ float tile[NN][NN + 1];
    for (int idx = threadIdx.x; idx < NN * NN; idx += 256)
        tile[idx / NN][idx % NN] = A[b * NN * NN + idx];
    __syncthreads();
    for (int idx = threadIdx.x; idx < NN * NN; idx += 256) {
        const int i = idx / NN, j = idx % NN;
        AT[b * NN * NN + idx] = tile[j][i];
    }
}

// ---------------- init: x = e = embed_W[tok]; e_proj = e@W1e; xjA = e@W1x ----------------
__global__ __launch_bounds__(128) void k_init(
    const int* __restrict__ tok, const float* __restrict__ embed_W,
    const float* __restrict__ W1, float* __restrict__ x,
    float* __restrict__ e_proj, float* __restrict__ xj)
{
    const int row = blockIdx.y * NN + blockIdx.x;
    const int t = threadIdx.x;
    __shared__ float e_s[DD];
    const float ev = embed_W[tok[row] * DD + t];
    e_s[t] = ev;
    x[row * DD + t] = ev;
    __syncthreads();
    float a1 = 0.f, a2 = 0.f;
#pragma unroll 8
    for (int k = 0; k < DD; ++k) {
        const float e = e_s[k];
        a1 = fmaf(e, W1[k * DD + t], a1);
        a2 = fmaf(e, W1[(DD + k) * DD + t], a2);
    }
    e_proj[row * DD + t] = a1;
    xj[row * DD + t]     = a2;
}

#define MFMA(A, B, C) __builtin_amdgcn_mfma_f32_16x16x32_bf16(A, B, C, 0, 0, 0)

// -------- persistent 3-unit pipelined round kernel --------
// Grid = 512 blocks = 16b x 32 i-slots = EXACTLY 2 blocks/CU, one generation, no tail.
// Block owns rows {is, is+32, is+64} of batch b. H double-buffered in LDS:
//   stage(0); bar; {stage(1) || GEMM(0)}; bar; {stage(2) || GEMM(1)}; bar; GEMM(2); bar;
//   then 3 deferred epilogues (pure VALU, overlaps co-resident block's GEMM).
// B-frags loaded once per kernel (3x amortized). v is one float4 register (k-pattern
// is t&31-constant) - no v_s LDS stage.
template<int FIN>
__global__ __launch_bounds__(512, 4) void k_round(
    const float* __restrict__ AT, const float* __restrict__ e_proj,
    const float* __restrict__ xj_in, const float* __restrict__ b1,
    const unsigned short* __restrict__ w2hi, const unsigned short* __restrict__ w2lo,
    const float* __restrict__ b2,
    const float* __restrict__ Wo1, const float* __restrict__ bo1,
    const float* __restrict__ Wo2, const float* __restrict__ embed_W,
    const float* __restrict__ W1x, const int* __restrict__ tau_p,
    float* __restrict__ x, float* __restrict__ xj_out,
    float* __restrict__ out, float* __restrict__ x_all)
{
    const int bx = blockIdx.x;   // 0..511
    const int b  = bx >> 5;      // batch 0..15
    const int is = bx & 31;      // i-slot: rows is, is+32, is+64
    const int t  = threadIdx.x;  // 0..511
    const int w  = t >> 6;       // wave = d-tile 0..7
    const int l  = t & 63;

    __shared__ __align__(16) unsigned short hs[2][NN * DD];  // 2 x 24 KB, XOR-swizzled
    __shared__ float ac_s[2][NN];
    __shared__ float agg_s[3][DD];
    __shared__ float xn_s[DD];
    __shared__ float part_s[4][DD];
    __shared__ float wred[2][NCLS];

    // B-fragments once per kernel, pinned
    const bf16x8* WH = (const bf16x8*)w2hi;
    const bf16x8* WL = (const bf16x8*)w2lo;
    const int f0 = (w * 4) * 64 + l;
    bf16x8 bh0 = WH[f0],       bl0 = WL[f0];
    bf16x8 bh1 = WH[f0 + 64],  bl1 = WL[f0 + 64];
    bf16x8 bh2 = WH[f0 + 128], bl2 = WL[f0 + 128];
    bf16x8 bh3 = WH[f0 + 192], bl3 = WL[f0 + 192];
    asm volatile("" : "+v"(bh0), "+v"(bh1), "+v"(bh2), "+v"(bh3),
                      "+v"(bl0), "+v"(bl1), "+v"(bl2), "+v"(bl3));
    const float b2v = b2[w * 16 + (l & 15)];
    const float4 b14 = *(const float4*)(b1 + ((t & 31) << 2));
    const float4* xj4 = (const float4*)(xj_in + b * NN * DD);

    // stage unit u into buffer p: H = relu(e_proj[row]+b1+xj) -> bf16, swizzled
    auto STAGE = [&](int u, int p) {
        const int row_u = (b * NN + is + 32 * u);
        const float4 ep = *(const float4*)(e_proj + row_u * DD + ((t & 31) << 2));
        float4 v4;
        v4.x = ep.x + b14.x; v4.y = ep.y + b14.y;
        v4.z = ep.z + b14.z; v4.w = ep.w + b14.w;
        if (t < NN) ac_s[p][t] = AT[row_u * NN + t];
#pragma unroll
        for (int it = 0; it < 6; ++it) {
            const int idx = t + it * 512;          // 0..3071; idx&31 == t&31
            const int j = idx >> 5, k4 = (idx & 31) << 2;
            const float4 u4 = xj4[idx];
            ushort4 hh;
            hh.x = f2bf(fmaxf(u4.x + v4.x, 0.f));
            hh.y = f2bf(fmaxf(u4.y + v4.y, 0.f));
            hh.z = f2bf(fmaxf(u4.z + v4.z, 0.f));
            hh.w = f2bf(fmaxf(u4.w + v4.w, 0.f));
            *(ushort4*)&hs[p][(j * DD + k4) ^ ((j & 7) << 3)] = hh;
        }
    };

    // GEMM unit u from buffer p: wave sweeps 6 j-tiles for its d-tile (hi+lo MFMA)
    auto GEMM = [&](int u, int p) {
        float aggp = 0.f;
        const unsigned short* hb = hs[p];
#pragma unroll
        for (int jt = 0; jt < 6; ++jt) {
            const int r16 = jt * 16 + (l & 15);
            const int ko  = (l >> 4) * 8;
            const int sw  = (r16 & 7) << 3;
            const bf16x8 a0 = *(const bf16x8*)&hb[(r16 * DD + ko     ) ^ sw];
            const bf16x8 a1 = *(const bf16x8*)&hb[(r16 * DD + ko + 32) ^ sw];
            const bf16x8 a2 = *(const bf16x8*)&hb[(r16 * DD + ko + 64) ^ sw];
            const bf16x8 a3 = *(const bf16x8*)&hb[(r16 * DD + ko + 96) ^ sw];
            f32x4 ch = {0.f, 0.f, 0.f, 0.f}, cl = {0.f, 0.f, 0.f, 0.f};
            ch = MFMA(a0, bh0, ch);  cl = MFMA(a0, bl0, cl);
            ch = MFMA(a1, bh1, ch);  cl = MFMA(a1, bl1, cl);
            ch = MFMA(a2, bh2, ch);  cl = MFMA(a2, bl2, cl);
            ch = MFMA(a3, bh3, ch);  cl = MFMA(a3, bl3, cl);
            const f32x4 m = ch + cl;
#pragma unroll
            for (int r = 0; r < 4; ++r) {
                const float a = ac_s[p][jt * 16 + (l >> 4) * 4 + r];
                aggp = fmaf(a, fmaxf(m[r] + b2v, 0.f), aggp);
            }
        }
        aggp += __shfl_xor(aggp, 16);
        aggp += __shfl_xor(aggp, 32);
        if (l < 16) agg_s[u][w * 16 + l] = aggp;
    };

    // ---- pipelined main: stage(u+1) issues under GEMM(u) ----
    STAGE(0, 0);
    __syncthreads();
    STAGE(1, 1);
    GEMM(0, 0);
    __syncthreads();
    STAGE(2, 0);
    GEMM(1, 1);
    __syncthreads();
    GEMM(2, 0);
    __syncthreads();

    // ---- 3 deferred epilogues: x-update + head (+discretize + next-round xj) ----
#pragma unroll 1
    for (int u = 0; u < 3; ++u) {
        const int row_u = b * NN + is + 32 * u;
        float xn = 0.f;
        if (t < DD) {
            xn = x[row_u * DD + t] + agg_s[u][t];
            xn_s[t] = xn;
        }
        __syncthreads();

        {   // hid partials: quarter q sums 32 k's for output h
            const int q = t >> 7, h = t & 127;
            float pp = 0.f;
#pragma unroll
            for (int kk = 0; kk < 32; ++kk) {
                const int k = q * 32 + kk;
                pp = fmaf(xn_s[k], Wo1[k * DD + h], pp);
            }
            part_s[q][h] = pp;
        }
        __syncthreads();

        if (t < DD) {   // waves 0,1 fully active: butterfly is safe
            const float hid = fmaxf(part_s[0][t] + part_s[1][t] + part_s[2][t]
                                    + part_s[3][t] + bo1[t], 0.f);
            float lgp[NCLS];
#pragma unroll
            for (int c = 0; c < NCLS; ++c) lgp[c] = hid * Wo2[t * NCLS + c];
#pragma unroll
            for (int s = 1; s < 64; s <<= 1) {
#pragma unroll
                for (int c = 0; c < NCLS; ++c) lgp[c] += __shfl_xor(lgp[c], s);
            }
            if (l == 0) {
#pragma unroll
                for (int c = 0; c < NCLS; ++c) wred[w][c] = lgp[c];
            }
        }
        __syncthreads();

        if (FIN) {
            if (t < NCLS) {
                const float lg = wred[0][t] + wred[1][t];
                x_all[row_u * NCLS + t] = lg;
                if ((row_u % NN) == 0) out[b * NCLS + t] = lg;
            }
            __syncthreads();
            continue;
        }

        // discretize: redundant per-thread softmax, then x += p @ centroids
        if (t < DD) {
            float lg[NCLS];
            float mx = -1e30f;
#pragma unroll
            for (int c = 0; c < NCLS; ++c) {
                lg[c] = wred[0][c] + wred[1][c];
                mx = fmaxf(mx, lg[c]);
            }
            const float inv_tau = 1.f / scalar_as_float(tau_p[0]);
            float p[NCLS], den = 0.f;
#pragma unroll
            for (int c = 0; c < NCLS; ++c) { p[c] = expf((lg[c] - mx) * inv_tau); den += p[c]; }
            const float invden = 1.f / den;
#pragma unroll
            for (int c = 0; c < NCLS; ++c)
                xn = fmaf(p[c] * invden, embed_W[(4 + c) * DD + t], xn);
            x[row_u * DD + t] = xn;
            xn_s[t] = xn;
        }
        __syncthreads();

        {   // next round's xj = xn @ W1x
            const int q = t >> 7, h = t & 127;
            float pp = 0.f;
#pragma unroll
            for (int kk = 0; kk < 32; ++kk) {
                const int k = q * 32 + kk;
                pp = fmaf(xn_s[k], W1x[k * DD + h], pp);
            }
            part_s[q][h] = pp;
        }
        __syncthreads();
        if (t < DD)
            xj_out[row_u * DD + t] = part_s[0][t] + part_s[1][t] + part_s[2][t] + part_s[3][t];
        __syncthreads();
    }
}

extern "C" void kernel_launch(void* const* d_in, const int* in_sizes, int n_in,
                              void* d_out, int out_size, void* d_ws, size_t ws_size,
                              hipStream_t stream)
{
    (void)in_sizes; (void)n_in; (void)out_size; (void)ws_size;
    const int*   tok     = (const int*)d_in[0];
    const float* Aab     = (const float*)d_in[1];
    const float* embed_W = (const float*)d_in[2];
    const float* W1      = (const float*)d_in[3];
    const float* b1      = (const float*)d_in[4];
    const float* W2      = (const float*)d_in[5];
    const float* b2      = (const float*)d_in[6];
    const float* Wo1     = (const float*)d_in[7];
    const float* bo1     = (const float*)d_in[8];
    const float* Wo2     = (const float*)d_in[9];
    const int*   tau_p   = (const int*)d_in[11];

    float* out   = (float*)d_out;
    float* x_all = out + BB * NCLS;

    float* ws     = (float*)d_ws;
    float* x      = ws;                                   // 196608 f
    float* e_proj = ws + BB * NN * DD;                    // 196608 f
    float* xjA    = ws + 2 * BB * NN * DD;                // 196608 f
    float* xjB    = ws + 3 * BB * NN * DD;                // 196608 f
    float* ATr    = ws + 4 * BB * NN * DD;                // 147456 f
    unsigned short* w2hi = (unsigned short*)(ws + 4 * BB * NN * DD + BB * NN * NN);
    unsigned short* w2lo = w2hi + DD * DD;

    const float* W1x = W1 + DD * DD;

    k_w2prep<<<8, 256, 0, stream>>>(W2, w2hi, w2lo);
    k_atrans<<<BB, 256, 0, stream>>>(Aab, ATr);
    {
        dim3 gi(NN, BB);
        k_init<<<gi, 128, 0, stream>>>(tok, embed_W, W1, x, e_proj, xjA);
    }
    for (int r = 0; r < 5; ++r) {
        const float* xin = (r & 1) ? xjB : xjA;
        float*       xot = (r & 1) ? xjA : xjB;
        if (r < 4)
            k_round<0><<<512, 512, 0, stream>>>(ATr, e_proj, xin, b1, w2hi, w2lo, b2,
                                                Wo1, bo1, Wo2, embed_W, W1x, tau_p,
                                                x, xot, out, x_all);
        else
            k_round<1><<<512, 512, 0, stream>>>(ATr, e_proj, xin, b1, w2hi, w2lo, b2,
                                                Wo1, bo1, Wo2, embed_W, W1x, tau_p,
                                                x, xot, out, x_all);
    }
}

// Round 9
// 123.653 us; speedup vs baseline: 1.3981x; 1.0339x over previous
//
#include <hip/hip_runtime.h>
#include <hip/hip_bf16.h>
#include <math.h>

#define BB   16
#define NN   96
#define DD   128
#define NCLS 10

typedef __attribute__((ext_vector_type(8))) short bf16x8;
typedef __attribute__((ext_vector_type(4))) float f32x4;

__device__ __forceinline__ float scalar_as_float(int v) {
    if (v >= -1000000 && v <= 1000000) return (float)v;
    return __int_as_float(v);
}
__device__ __forceinline__ unsigned short f2bf(float f) {
    unsigned u = __float_as_uint(f);
    return (unsigned short)((u + 0x7FFFu + ((u >> 16) & 1u)) >> 16);
}
__device__ __forceinline__ float bf2f(unsigned short h) {
    return __uint_as_float(((unsigned)h) << 16);
}

// ---------------- one-time: pack W2 into MFMA B-fragments, bf16 hi + lo ----------------
// frag-major: [dtile 0..7][kchunk 0..3][lane 0..63][e 0..7]
// B-frag (16x16x32): lane l holds B[k = kc*32 + (l>>4)*8 + e][col = dt*16 + (l&15)]
__global__ __launch_bounds__(256) void k_w2prep(
    const float* __restrict__ W2, unsigned short* __restrict__ whi,
    unsigned short* __restrict__ wlo)
{
    const int dt = blockIdx.x;
    const int kc = threadIdx.x >> 6;
    const int l  = threadIdx.x & 63;
    const int base = ((dt * 4 + kc) * 64 + l) * 8;
    const int c = dt * 16 + (l & 15);
#pragma unroll
    for (int e = 0; e < 8; ++e) {
        const int k = kc * 32 + (l >> 4) * 8 + e;
        const float wv = W2[k * DD + c];
        const unsigned short h = f2bf(wv);
        whi[base + e] = h;
        wlo[base + e] = f2bf(wv - bf2f(h));
    }
}

// ---------------- one-time: AT[b][i][j] = A[b][j][i] ----------------
__global__ __launch_bounds__(256) void k_atrans(
    const float* __restrict__ A, float* __restrict__ AT)
{
    const int b = blockIdx.x;
    __shared__ float tile[NN][NN + 1];
    for (int idx = threadIdx.x; idx < NN * NN; idx += 256)
        tile[idx / NN][idx % NN] = A[b * NN * NN + idx];
    __syncthreads();
    for (int idx = threadIdx.x; idx < NN * NN; idx += 256) {
        const int i = idx / NN, j = idx % NN;
        AT[b * NN * NN + idx] = tile[j][i];
    }
}

// ---------------- init: x = e = embed_W[tok]; e_proj = e@W1e; xjA = e@W1x ----------------
__global__ __launch_bounds__(128) void k_init(
    const int* __restrict__ tok, const float* __restrict__ embed_W,
    const float* __restrict__ W1, float* __restrict__ x,
    float* __restrict__ e_proj, float* __restrict__ xj)
{
    const int row = blockIdx.y * NN + blockIdx.x;
    const int t = threadIdx.x;
    __shared__ float e_s[DD];
    const float ev = embed_W[tok[row] * DD + t];
    e_s[t] = ev;
    x[row * DD + t] = ev;
    __syncthreads();
    float a1 = 0.f, a2 = 0.f;
#pragma unroll 8
    for (int k = 0; k < DD; ++k) {
        const float e = e_s[k];
        a1 = fmaf(e, W1[k * DD + t], a1);
        a2 = fmaf(e, W1[(DD + k) * DD + t], a2);
    }
    e_proj[row * DD + t] = a1;
    xj[row * DD + t]     = a2;
}

#define MFMA(A, B, C) __builtin_amdgcn_mfma_f32_16x16x32_bf16(A, B, C, 0, 0, 0)

// -------- persistent 3-unit pipelined round kernel, 3j x 2d wave split --------
// Grid = 512 = 16b x 32 i-slots = exactly 2 blocks/CU. Block owns rows {is, is+32, is+64}.
// 8 waves = 2 j-groups(3 j-tiles) x 4 d-groups(d-tiles dg, dg+4): each wave reads only
// HALF of H from LDS (12KB) -> GEMM LDS traffic halves vs 6jx1d. 16 B-frags (64 VGPR)
// pinned; hi/lo folded into ONE accumulator chain per d-tile (C-regs 16->8).
// Epilogue batched over the 3 rows: Wo1/W1x read once, 3 accumulators (L2 traffic /3).
template<int FIN>
__global__ __launch_bounds__(512, 4) void k_round(
    const float* __restrict__ AT, const float* __restrict__ e_proj,
    const float* __restrict__ xj_in, const float* __restrict__ b1,
    const unsigned short* __restrict__ w2hi, const unsigned short* __restrict__ w2lo,
    const float* __restrict__ b2,
    const float* __restrict__ Wo1, const float* __restrict__ bo1,
    const float* __restrict__ Wo2, const float* __restrict__ embed_W,
    const float* __restrict__ W1x, const int* __restrict__ tau_p,
    float* __restrict__ x, float* __restrict__ xj_out,
    float* __restrict__ out, float* __restrict__ x_all)
{
    const int bx = blockIdx.x;   // 0..511
    const int b  = bx >> 5;      // batch 0..15
    const int is = bx & 31;      // rows is, is+32, is+64
    const int t  = threadIdx.x;  // 0..511
    const int w  = t >> 6;       // wave 0..7
    const int l  = t & 63;
    const int jg  = w >> 2;      // j-group 0..1 (3 j-tiles each)
    const int dg  = w & 3;       // d-group 0..3 (d-tiles dg, dg+4)
    const int jg3 = jg * 3;

    __shared__ __align__(16) unsigned short hs[2][NN * DD];  // 2 x 24 KB, XOR-swizzled
    __shared__ float ac_s[2][NN];
    __shared__ float agg_part[3][2][DD];   // [unit][jg][d]
    __shared__ float xn_s[3][DD];
    __shared__ float part_s[4][3][DD];     // [quarter][unit][h]
    __shared__ float wred[2][3][NCLS];     // [feature-half][unit][class]

    // B-fragments: 2 d-tiles x 4 kc x hi/lo = 16 frags = 64 VGPR, pinned once
    const bf16x8* WH = (const bf16x8*)w2hi;
    const bf16x8* WL = (const bf16x8*)w2lo;
    const int f0 = (dg * 4) * 64 + l;
    const int f1 = ((dg + 4) * 4) * 64 + l;
    bf16x8 bh00 = WH[f0],        bl00 = WL[f0];
    bf16x8 bh01 = WH[f0 + 64],   bl01 = WL[f0 + 64];
    bf16x8 bh02 = WH[f0 + 128],  bl02 = WL[f0 + 128];
    bf16x8 bh03 = WH[f0 + 192],  bl03 = WL[f0 + 192];
    bf16x8 bh10 = WH[f1],        bl10 = WL[f1];
    bf16x8 bh11 = WH[f1 + 64],   bl11 = WL[f1 + 64];
    bf16x8 bh12 = WH[f1 + 128],  bl12 = WL[f1 + 128];
    bf16x8 bh13 = WH[f1 + 192],  bl13 = WL[f1 + 192];
    asm volatile("" : "+v"(bh00), "+v"(bh01), "+v"(bh02), "+v"(bh03),
                      "+v"(bl00), "+v"(bl01), "+v"(bl02), "+v"(bl03),
                      "+v"(bh10), "+v"(bh11), "+v"(bh12), "+v"(bh13),
                      "+v"(bl10), "+v"(bl11), "+v"(bl12), "+v"(bl13));
    const float b2v0 = b2[dg * 16 + (l & 15)];
    const float b2v1 = b2[64 + dg * 16 + (l & 15)];
    const float4 b14 = *(const float4*)(b1 + ((t & 31) << 2));
    const float4* xj4 = (const float4*)(xj_in + b * NN * DD);

    // stage unit u into buffer p: H = relu(e_proj[row]+b1+xj) -> bf16, swizzled
    auto STAGE = [&](int u, int p) {
        const int row_u = (b * NN + is + 32 * u);
        const float4 ep = *(const float4*)(e_proj + row_u * DD + ((t & 31) << 2));
        float4 v4;
        v4.x = ep.x + b14.x; v4.y = ep.y + b14.y;
        v4.z = ep.z + b14.z; v4.w = ep.w + b14.w;
        if (t < NN) ac_s[p][t] = AT[row_u * NN + t];
#pragma unroll
        for (int it = 0; it < 6; ++it) {
            const int idx = t + it * 512;          // idx&31 == t&31
            const int j = idx >> 5, k4 = (idx & 31) << 2;
            const float4 u4 = xj4[idx];
            ushort4 hh;
            hh.x = f2bf(fmaxf(u4.x + v4.x, 0.f));
            hh.y = f2bf(fmaxf(u4.y + v4.y, 0.f));
            hh.z = f2bf(fmaxf(u4.z + v4.z, 0.f));
            hh.w = f2bf(fmaxf(u4.w + v4.w, 0.f));
            *(ushort4*)&hs[p][(j * DD + k4) ^ ((j & 7) << 3)] = hh;
        }
    };

    // GEMM unit u from buffer p: wave does 3 j-tiles x 2 d-tiles, single acc chain/dt
    auto GEMM = [&](int u, int p) {
        float aggp0 = 0.f, aggp1 = 0.f;
        const unsigned short* hb = hs[p];
#pragma unroll
        for (int jj = 0; jj < 3; ++jj) {
            const int jt  = jg3 + jj;
            const int r16 = jt * 16 + (l & 15);
            const int ko  = (l >> 4) * 8;
            const int sw  = (r16 & 7) << 3;
            const bf16x8 a0 = *(const bf16x8*)&hb[(r16 * DD + ko     ) ^ sw];
            const bf16x8 a1 = *(const bf16x8*)&hb[(r16 * DD + ko + 32) ^ sw];
            const bf16x8 a2 = *(const bf16x8*)&hb[(r16 * DD + ko + 64) ^ sw];
            const bf16x8 a3 = *(const bf16x8*)&hb[(r16 * DD + ko + 96) ^ sw];
            f32x4 c0 = {0.f, 0.f, 0.f, 0.f}, c1 = {0.f, 0.f, 0.f, 0.f};
            c0 = MFMA(a0, bh00, c0);  c1 = MFMA(a0, bh10, c1);
            c0 = MFMA(a0, bl00, c0);  c1 = MFMA(a0, bl10, c1);
            c0 = MFMA(a1, bh01, c0);  c1 = MFMA(a1, bh11, c1);
            c0 = MFMA(a1, bl01, c0);  c1 = MFMA(a1, bl11, c1);
            c0 = MFMA(a2, bh02, c0);  c1 = MFMA(a2, bh12, c1);
            c0 = MFMA(a2, bl02, c0);  c1 = MFMA(a2, bl12, c1);
            c0 = MFMA(a3, bh03, c0);  c1 = MFMA(a3, bh13, c1);
            c0 = MFMA(a3, bl03, c0);  c1 = MFMA(a3, bl13, c1);
#pragma unroll
            for (int r = 0; r < 4; ++r) {
                const float a = ac_s[p][jt * 16 + (l >> 4) * 4 + r];
                aggp0 = fmaf(a, fmaxf(c0[r] + b2v0, 0.f), aggp0);
                aggp1 = fmaf(a, fmaxf(c1[r] + b2v1, 0.f), aggp1);
            }
        }
        aggp0 += __shfl_xor(aggp0, 16); aggp0 += __shfl_xor(aggp0, 32);
        aggp1 += __shfl_xor(aggp1, 16); aggp1 += __shfl_xor(aggp1, 32);
        if (l < 16) {
            agg_part[u][jg][dg * 16 + l]      = aggp0;
            agg_part[u][jg][64 + dg * 16 + l] = aggp1;
        }
    };

    // ---- pipelined main ----
    STAGE(0, 0);
    __syncthreads();
    STAGE(1, 1);
    GEMM(0, 0);
    __syncthreads();
    STAGE(2, 0);
    GEMM(1, 1);
    __syncthreads();
    GEMM(2, 0);
    __syncthreads();

    // ---- batched epilogue over the 3 rows ----
    const int u6 = w >> 1;                  // row unit for wave-pair (valid w<6)
    const int tt = ((w & 1) << 6) | l;      // feature 0..127
    const int row0 = b * NN + is;

    // P1: xn = x + agg
    if (w < 6)
        xn_s[u6][tt] = x[(row0 + 32 * u6) * DD + tt]
                     + agg_part[u6][0][tt] + agg_part[u6][1][tt];
    __syncthreads();

    // P2: hid partials — Wo1 read ONCE, applied to 3 rows
    {
        const int q = t >> 7, h = t & 127;
        float p0 = 0.f, p1 = 0.f, p2 = 0.f;
#pragma unroll
        for (int kk = 0; kk < 32; ++kk) {
            const int k = q * 32 + kk;
            const float wv = Wo1[k * DD + h];
            p0 = fmaf(xn_s[0][k], wv, p0);
            p1 = fmaf(xn_s[1][k], wv, p1);
            p2 = fmaf(xn_s[2][k], wv, p2);
        }
        part_s[q][0][h] = p0; part_s[q][1][h] = p1; part_s[q][2][h] = p2;
    }
    __syncthreads();

    // P3: hid + logits, wave-pair per row, 64-lane butterfly per feature-half
    if (w < 6) {
        const float hid = fmaxf(part_s[0][u6][tt] + part_s[1][u6][tt]
                              + part_s[2][u6][tt] + part_s[3][u6][tt] + bo1[tt], 0.f);
        float lgp[NCLS];
#pragma unroll
        for (int c = 0; c < NCLS; ++c) lgp[c] = hid * Wo2[tt * NCLS + c];
#pragma unroll
        for (int s = 1; s < 64; s <<= 1) {
#pragma unroll
            for (int c = 0; c < NCLS; ++c) lgp[c] += __shfl_xor(lgp[c], s);
        }
        if (l == 0) {
#pragma unroll
            for (int c = 0; c < NCLS; ++c) wred[w & 1][u6][c] = lgp[c];
        }
    }
    __syncthreads();

    if (FIN) {
        if (w < 6 && (w & 1) == 0 && l < NCLS) {
            const float lg = wred[0][u6][l] + wred[1][u6][l];
            x_all[(row0 + 32 * u6) * NCLS + l] = lg;
            if (is == 0 && u6 == 0) out[b * NCLS + l] = lg;
        }
        return;
    }

    // P4: softmax + x-update (wave-pair per row, redundant per-thread softmax)
    if (w < 6) {
        float lg[NCLS];
        float mx = -1e30f;
#pragma unroll
        for (int c = 0; c < NCLS; ++c) {
            lg[c] = wred[0][u6][c] + wred[1][u6][c];
            mx = fmaxf(mx, lg[c]);
        }
        const float inv_tau = 1.f / scalar_as_float(tau_p[0]);
        float p[NCLS], den = 0.f;
#pragma unroll
        for (int c = 0; c < NCLS; ++c) { p[c] = expf((lg[c] - mx) * inv_tau); den += p[c]; }
        const float invden = 1.f / den;
        float xnu = xn_s[u6][tt];
#pragma unroll
        for (int c = 0; c < NCLS; ++c)
            xnu = fmaf(p[c] * invden, embed_W[(4 + c) * DD + tt], xnu);
        x[(row0 + 32 * u6) * DD + tt] = xnu;
        xn_s[u6][tt] = xnu;     // same-thread RAW only; cross-thread reads after barrier
    }
    __syncthreads();

    // P5: next-round xj partials — W1x read ONCE, 3 rows
    {
        const int q = t >> 7, h = t & 127;
        float p0 = 0.f, p1 = 0.f, p2 = 0.f;
#pragma unroll
        for (int kk = 0; kk < 32; ++kk) {
            const int k = q * 32 + kk;
            const float wv = W1x[k * DD + h];
            p0 = fmaf(xn_s[0][k], wv, p0);
            p1 = fmaf(xn_s[1][k], wv, p1);
            p2 = fmaf(xn_s[2][k], wv, p2);
        }
        part_s[q][0][h] = p0; part_s[q][1][h] = p1; part_s[q][2][h] = p2;
    }
    __syncthreads();

    // P6: gather + store xj
    if (w < 6)
        xj_out[(row0 + 32 * u6) * DD + tt] = part_s[0][u6][tt] + part_s[1][u6][tt]
                                           + part_s[2][u6][tt] + part_s[3][u6][tt];
}

extern "C" void kernel_launch(void* const* d_in, const int* in_sizes, int n_in,
                              void* d_out, int out_size, void* d_ws, size_t ws_size,
                              hipStream_t stream)
{
    (void)in_sizes; (void)n_in; (void)out_size; (void)ws_size;
    const int*   tok     = (const int*)d_in[0];
    const float* Aab     = (const float*)d_in[1];
    const float* embed_W = (const float*)d_in[2];
    const float* W1      = (const float*)d_in[3];
    const float* b1      = (const float*)d_in[4];
    const float* W2      = (const float*)d_in[5];
    const float* b2      = (const float*)d_in[6];
    const float* Wo1     = (const float*)d_in[7];
    const float* bo1     = (const float*)d_in[8];
    const float* Wo2     = (const float*)d_in[9];
    const int*   tau_p   = (const int*)d_in[11];

    float* out   = (float*)d_out;
    float* x_all = out + BB * NCLS;

    float* ws     = (float*)d_ws;
    float* x      = ws;                                   // 196608 f
    float* e_proj = ws + BB * NN * DD;                    // 196608 f
    float* xjA    = ws + 2 * BB * NN * DD;                // 196608 f
    float* xjB    = ws + 3 * BB * NN * DD;                // 196608 f
    float* ATr    = ws + 4 * BB * NN * DD;                // 147456 f
    unsigned short* w2hi = (unsigned short*)(ws + 4 * BB * NN * DD + BB * NN * NN);
    unsigned short* w2lo = w2hi + DD * DD;

    const float* W1x = W1 + DD * DD;

    k_w2prep<<<8, 256, 0, stream>>>(W2, w2hi, w2lo);
    k_atrans<<<BB, 256, 0, stream>>>(Aab, ATr);
    {
        dim3 gi(NN, BB);
        k_init<<<gi, 128, 0, stream>>>(tok, embed_W, W1, x, e_proj, xjA);
    }
    for (int r = 0; r < 5; ++r) {
        const float* xin = (r & 1) ? xjB : xjA;
        float*       xot = (r & 1) ? xjA : xjB;
        if (r < 4)
            k_round<0><<<512, 512, 0, stream>>>(ATr, e_proj, xin, b1, w2hi, w2lo, b2,
                                                Wo1, bo1, Wo2, embed_W, W1x, tau_p,
                                                x, xot, out, x_all);
        else
            k_round<1><<<512, 512, 0, stream>>>(ATr, e_proj, xin, b1, w2hi, w2lo, b2,
                                                Wo1, bo1, Wo2, embed_W, W1x, tau_p,
                                                x, xot, out, x_all);
    }
}

// Round 10
// 100.979 us; speedup vs baseline: 1.7121x; 1.2245x over previous
//
#include <hip/hip_runtime.h>
#include <hip/hip_bf16.h>
#include <math.h>

#define BB   16
#define NN   96
#define DD   128
#define NCLS 10

typedef __attribute__((ext_vector_type(8))) short bf16x8;
typedef __attribute__((ext_vector_type(8))) unsigned short u16x8;
typedef __attribute__((ext_vector_type(4))) float f32x4;

__device__ __forceinline__ float scalar_as_float(int v) {
    if (v >= -1000000 && v <= 1000000) return (float)v;
    return __int_as_float(v);
}
__device__ __forceinline__ unsigned short f2bf(float f) {
    unsigned u = __float_as_uint(f);
    return (unsigned short)((u + 0x7FFFu + ((u >> 16) & 1u)) >> 16);
}
__device__ __forceinline__ float bf2f(unsigned short h) {
    return __uint_as_float(((unsigned)h) << 16);
}

// ---------------- one-time: pack W2 into MFMA B-fragments, single bf16 ----------------
// frag-major: [dtile 0..7][kchunk 0..3][lane 0..63][e 0..7]
// B-frag (16x16x32): lane l holds B[k = kc*32 + (l>>4)*8 + e][col = dt*16 + (l&15)]
__global__ __launch_bounds__(256) void k_w2prep(
    const float* __restrict__ W2, unsigned short* __restrict__ whi)
{
    const int dt = blockIdx.x;
    const int kc = threadIdx.x >> 6;
    const int l  = threadIdx.x & 63;
    const int base = ((dt * 4 + kc) * 64 + l) * 8;
    const int c = dt * 16 + (l & 15);
#pragma unroll
    for (int e = 0; e < 8; ++e) {
        const int k = kc * 32 + (l >> 4) * 8 + e;
        whi[base + e] = f2bf(W2[k * DD + c]);
    }
}

// ---------------- one-time: AT[b][i][j] = A[b][j][i] ----------------
__global__ __launch_bounds__(256) void k_atrans(
    const float* __restrict__ A, float* __restrict__ AT)
{
    const int b = blockIdx.x;
    __shared__ float tile[NN][NN + 1];
    for (int idx = threadIdx.x; idx < NN * NN; idx += 256)
        tile[idx / NN][idx % NN] = A[b * NN * NN + idx];
    __syncthreads();
    for (int idx = threadIdx.x; idx < NN * NN; idx += 256) {
        const int i = idx / NN, j = idx % NN;
        AT[b * NN * NN + idx] = tile[j][i];
    }
}

// ------- init: x = e = embed_W[tok]; e_proj = e@W1e (f32); xjA = bf16(e@W1x) -------
__global__ __launch_bounds__(128) void k_init(
    const int* __restrict__ tok, const float* __restrict__ embed_W,
    const float* __restrict__ W1, float* __restrict__ x,
    float* __restrict__ e_proj, unsigned short* __restrict__ xj)
{
    const int row = blockIdx.y * NN + blockIdx.x;
    const int t = threadIdx.x;
    __shared__ float e_s[DD];
    const float ev = embed_W[tok[row] * DD + t];
    e_s[t] = ev;
    x[row * DD + t] = ev;
    __syncthreads();
    float a1 = 0.f, a2 = 0.f;
#pragma unroll 8
    for (int k = 0; k < DD; ++k) {
        const float e = e_s[k];
        a1 = fmaf(e, W1[k * DD + t], a1);
        a2 = fmaf(e, W1[(DD + k) * DD + t], a2);
    }
    e_proj[row * DD + t] = a1;
    xj[row * DD + t]     = f2bf(a2);
}

#define MFMA(A, B, C) __builtin_amdgcn_mfma_f32_16x16x32_bf16(A, B, C, 0, 0, 0)

// -------- persistent 3-unit pipelined round kernel, 3j x 2d wave split --------
// Grid = 512 = 16b x 32 i-slots = exactly 2 blocks/CU. Block owns rows {is, is+32, is+64}.
// Single-bf16 W2 (8 frags, pinned): MFMA work halved vs hi/lo. xj stored bf16:
// STAGE L2 read halved. Both rely on threshold slack (R9 absmax 8192 vs 37.8K limit).
template<int FIN>
__global__ __launch_bounds__(512, 4) void k_round(
    const float* __restrict__ AT, const float* __restrict__ e_proj,
    const unsigned short* __restrict__ xj_in, const float* __restrict__ b1,
    const unsigned short* __restrict__ w2hi,
    const float* __restrict__ b2,
    const float* __restrict__ Wo1, const float* __restrict__ bo1,
    const float* __restrict__ Wo2, const float* __restrict__ embed_W,
    const float* __restrict__ W1x, const int* __restrict__ tau_p,
    float* __restrict__ x, unsigned short* __restrict__ xj_out,
    float* __restrict__ out, float* __restrict__ x_all)
{
    const int bx = blockIdx.x;   // 0..511
    const int b  = bx >> 5;      // batch 0..15
    const int is = bx & 31;      // rows is, is+32, is+64
    const int t  = threadIdx.x;  // 0..511
    const int w  = t >> 6;       // wave 0..7
    const int l  = t & 63;
    const int jg  = w >> 2;      // j-group 0..1 (3 j-tiles each)
    const int dg  = w & 3;       // d-group 0..3 (d-tiles dg, dg+4)
    const int jg3 = jg * 3;

    __shared__ __align__(16) unsigned short hs[2][NN * DD];  // 2 x 24 KB, XOR-swizzled
    __shared__ float ac_s[2][NN];
    __shared__ float agg_part[3][2][DD];   // [unit][jg][d]
    __shared__ float xn_s[3][DD];
    __shared__ float part_s[4][3][DD];     // [quarter][unit][h]
    __shared__ float wred[2][3][NCLS];     // [feature-half][unit][class]

    // B-fragments: 2 d-tiles x 4 kc = 8 frags = 32 VGPR, pinned once
    const bf16x8* WH = (const bf16x8*)w2hi;
    const int f0 = (dg * 4) * 64 + l;
    const int f1 = ((dg + 4) * 4) * 64 + l;
    bf16x8 bh00 = WH[f0],        bh10 = WH[f1];
    bf16x8 bh01 = WH[f0 + 64],   bh11 = WH[f1 + 64];
    bf16x8 bh02 = WH[f0 + 128],  bh12 = WH[f1 + 128];
    bf16x8 bh03 = WH[f0 + 192],  bh13 = WH[f1 + 192];
    asm volatile("" : "+v"(bh00), "+v"(bh01), "+v"(bh02), "+v"(bh03),
                      "+v"(bh10), "+v"(bh11), "+v"(bh12), "+v"(bh13));
    const float b2v0 = b2[dg * 16 + (l & 15)];
    const float b2v1 = b2[64 + dg * 16 + (l & 15)];
    const int d0 = (t & 15) * 8;            // 8-wide d-slice this thread stages
    const float4 b4a = *(const float4*)(b1 + d0);
    const float4 b4b = *(const float4*)(b1 + d0 + 4);
    const u16x8* xj8 = (const u16x8*)(xj_in + b * NN * DD);

    // stage unit u into buffer p: H = relu(e_proj[row]+b1+xj) -> bf16, swizzled
    auto STAGE = [&](int u, int p) {
        const int row_u = (b * NN + is + 32 * u);
        const float4 ea = *(const float4*)(e_proj + row_u * DD + d0);
        const float4 eb = *(const float4*)(e_proj + row_u * DD + d0 + 4);
        float v8[8];
        v8[0] = ea.x + b4a.x; v8[1] = ea.y + b4a.y;
        v8[2] = ea.z + b4a.z; v8[3] = ea.w + b4a.w;
        v8[4] = eb.x + b4b.x; v8[5] = eb.y + b4b.y;
        v8[6] = eb.z + b4b.z; v8[7] = eb.w + b4b.w;
        if (t < NN) ac_s[p][t] = AT[row_u * NN + t];
#pragma unroll
        for (int it = 0; it < 3; ++it) {
            const int idx8 = t + it * 512;     // u16x8 index; (idx8&15)*8 == d0
            const int j = idx8 >> 4;
            const u16x8 xv = xj8[idx8];
            u16x8 hh;
#pragma unroll
            for (int e = 0; e < 8; ++e)
                hh[e] = f2bf(fmaxf(bf2f(xv[e]) + v8[e], 0.f));
            *(u16x8*)&hs[p][(j * DD + d0) ^ ((j & 7) << 3)] = hh;
        }
    };

    // GEMM unit u from buffer p: wave does 3 j-tiles x 2 d-tiles
    auto GEMM = [&](int u, int p) {
        float aggp0 = 0.f, aggp1 = 0.f;
        const unsigned short* hb = hs[p];
#pragma unroll
        for (int jj = 0; jj < 3; ++jj) {
            const int jt  = jg3 + jj;
            const int r16 = jt * 16 + (l & 15);
            const int ko  = (l >> 4) * 8;
            const int sw  = (r16 & 7) << 3;
            const bf16x8 a0 = *(const bf16x8*)&hb[(r16 * DD + ko     ) ^ sw];
            const bf16x8 a1 = *(const bf16x8*)&hb[(r16 * DD + ko + 32) ^ sw];
            const bf16x8 a2 = *(const bf16x8*)&hb[(r16 * DD + ko + 64) ^ sw];
            const bf16x8 a3 = *(const bf16x8*)&hb[(r16 * DD + ko + 96) ^ sw];
            f32x4 c0 = {0.f, 0.f, 0.f, 0.f}, c1 = {0.f, 0.f, 0.f, 0.f};
            c0 = MFMA(a0, bh00, c0);  c1 = MFMA(a0, bh10, c1);
            c0 = MFMA(a1, bh01, c0);  c1 = MFMA(a1, bh11, c1);
            c0 = MFMA(a2, bh02, c0);  c1 = MFMA(a2, bh12, c1);
            c0 = MFMA(a3, bh03, c0);  c1 = MFMA(a3, bh13, c1);
#pragma unroll
            for (int r = 0; r < 4; ++r) {
                const float a = ac_s[p][jt * 16 + (l >> 4) * 4 + r];
                aggp0 = fmaf(a, fmaxf(c0[r] + b2v0, 0.f), aggp0);
                aggp1 = fmaf(a, fmaxf(c1[r] + b2v1, 0.f), aggp1);
            }
        }
        aggp0 += __shfl_xor(aggp0, 16); aggp0 += __shfl_xor(aggp0, 32);
        aggp1 += __shfl_xor(aggp1, 16); aggp1 += __shfl_xor(aggp1, 32);
        if (l < 16) {
            agg_part[u][jg][dg * 16 + l]      = aggp0;
            agg_part[u][jg][64 + dg * 16 + l] = aggp1;
        }
    };

    // ---- pipelined main ----
    STAGE(0, 0);
    __syncthreads();
    STAGE(1, 1);
    GEMM(0, 0);
    __syncthreads();
    STAGE(2, 0);
    GEMM(1, 1);
    __syncthreads();
    GEMM(2, 0);
    __syncthreads();

    // ---- batched epilogue over the 3 rows ----
    const int u6 = w >> 1;                  // row unit for wave-pair (valid w<6)
    const int tt = ((w & 1) << 6) | l;      // feature 0..127
    const int row0 = b * NN + is;

    // P1: xn = x + agg
    if (w < 6)
        xn_s[u6][tt] = x[(row0 + 32 * u6) * DD + tt]
                     + agg_part[u6][0][tt] + agg_part[u6][1][tt];
    __syncthreads();

    // P2: hid partials — Wo1 read ONCE, applied to 3 rows
    {
        const int q = t >> 7, h = t & 127;
        float p0 = 0.f, p1 = 0.f, p2 = 0.f;
#pragma unroll
        for (int kk = 0; kk < 32; ++kk) {
            const int k = q * 32 + kk;
            const float wv = Wo1[k * DD + h];
            p0 = fmaf(xn_s[0][k], wv, p0);
            p1 = fmaf(xn_s[1][k], wv, p1);
            p2 = fmaf(xn_s[2][k], wv, p2);
        }
        part_s[q][0][h] = p0; part_s[q][1][h] = p1; part_s[q][2][h] = p2;
    }
    __syncthreads();

    // P3: hid + logits, wave-pair per row, 64-lane butterfly per feature-half
    if (w < 6) {
        const float hid = fmaxf(part_s[0][u6][tt] + part_s[1][u6][tt]
                              + part_s[2][u6][tt] + part_s[3][u6][tt] + bo1[tt], 0.f);
        float lgp[NCLS];
#pragma unroll
        for (int c = 0; c < NCLS; ++c) lgp[c] = hid * Wo2[tt * NCLS + c];
#pragma unroll
        for (int s = 1; s < 64; s <<= 1) {
#pragma unroll
            for (int c = 0; c < NCLS; ++c) lgp[c] += __shfl_xor(lgp[c], s);
        }
        if (l == 0) {
#pragma unroll
            for (int c = 0; c < NCLS; ++c) wred[w & 1][u6][c] = lgp[c];
        }
    }
    __syncthreads();

    if (FIN) {
        if (w < 6 && (w & 1) == 0 && l < NCLS) {
            const float lg = wred[0][u6][l] + wred[1][u6][l];
            x_all[(row0 + 32 * u6) * NCLS + l] = lg;
            if (is == 0 && u6 == 0) out[b * NCLS + l] = lg;
        }
        return;
    }

    // P4: softmax + x-update (wave-pair per row, redundant per-thread softmax)
    if (w < 6) {
        float lg[NCLS];
        float mx = -1e30f;
#pragma unroll
        for (int c = 0; c < NCLS; ++c) {
            lg[c] = wred[0][u6][c] + wred[1][u6][c];
            mx = fmaxf(mx, lg[c]);
        }
        const float inv_tau = 1.f / scalar_as_float(tau_p[0]);
        float p[NCLS], den = 0.f;
#pragma unroll
        for (int c = 0; c < NCLS; ++c) { p[c] = expf((lg[c] - mx) * inv_tau); den += p[c]; }
        const float invden = 1.f / den;
        float xnu = xn_s[u6][tt];
#pragma unroll
        for (int c = 0; c < NCLS; ++c)
            xnu = fmaf(p[c] * invden, embed_W[(4 + c) * DD + tt], xnu);
        x[(row0 + 32 * u6) * DD + tt] = xnu;
        xn_s[u6][tt] = xnu;     // same-thread RAW only; cross-thread reads after barrier
    }
    __syncthreads();

    // P5: next-round xj partials — W1x read ONCE, 3 rows
    {
        const int q = t >> 7, h = t & 127;
        float p0 = 0.f, p1 = 0.f, p2 = 0.f;
#pragma unroll
        for (int kk = 0; kk < 32; ++kk) {
            const int k = q * 32 + kk;
            const float wv = W1x[k * DD + h];
            p0 = fmaf(xn_s[0][k], wv, p0);
            p1 = fmaf(xn_s[1][k], wv, p1);
            p2 = fmaf(xn_s[2][k], wv, p2);
        }
        part_s[q][0][h] = p0; part_s[q][1][h] = p1; part_s[q][2][h] = p2;
    }
    __syncthreads();

    // P6: gather + store xj as bf16
    if (w < 6)
        xj_out[(row0 + 32 * u6) * DD + tt] =
            f2bf(part_s[0][u6][tt] + part_s[1][u6][tt]
               + part_s[2][u6][tt] + part_s[3][u6][tt]);
}

extern "C" void kernel_launch(void* const* d_in, const int* in_sizes, int n_in,
                              void* d_out, int out_size, void* d_ws, size_t ws_size,
                              hipStream_t stream)
{
    (void)in_sizes; (void)n_in; (void)out_size; (void)ws_size;
    const int*   tok     = (const int*)d_in[0];
    const float* Aab     = (const float*)d_in[1];
    const float* embed_W = (const float*)d_in[2];
    const float* W1      = (const float*)d_in[3];
    const float* b1      = (const float*)d_in[4];
    const float* W2      = (const float*)d_in[5];
    const float* b2      = (const float*)d_in[6];
    const float* Wo1     = (const float*)d_in[7];
    const float* bo1     = (const float*)d_in[8];
    const float* Wo2     = (const float*)d_in[9];
    const int*   tau_p   = (const int*)d_in[11];

    float* out   = (float*)d_out;
    float* x_all = out + BB * NCLS;

    float* ws     = (float*)d_ws;
    float* x      = ws;                                   // 196608 f
    float* e_proj = ws + BB * NN * DD;                    // 196608 f
    float* ATr    = ws + 2 * BB * NN * DD;                // 147456 f
    unsigned short* xjA  = (unsigned short*)(ws + 2 * BB * NN * DD + BB * NN * NN);
    unsigned short* xjB  = xjA + BB * NN * DD;            // 196608 u16 each
    unsigned short* w2hi = xjB + BB * NN * DD;            // 16384 u16

    const float* W1x = W1 + DD * DD;

    k_w2prep<<<8, 256, 0, stream>>>(W2, w2hi);
    k_atrans<<<BB, 256, 0, stream>>>(Aab, ATr);
    {
        dim3 gi(NN, BB);
        k_init<<<gi, 128, 0, stream>>>(tok, embed_W, W1, x, e_proj, xjA);
    }
    for (int r = 0; r < 5; ++r) {
        const unsigned short* xin = (r & 1) ? xjB : xjA;
        unsigned short*       xot = (r & 1) ? xjA : xjB;
        if (r < 4)
            k_round<0><<<512, 512, 0, stream>>>(ATr, e_proj, xin, b1, w2hi, b2,
                                                Wo1, bo1, Wo2, embed_W, W1x, tau_p,
                                                x, xot, out, x_all);
        else
            k_round<1><<<512, 512, 0, stream>>>(ATr, e_proj, xin, b1, w2hi, b2,
                                                Wo1, bo1, Wo2, embed_W, W1x, tau_p,
                                                x, xot, out, x_all);
    }
}